// Round 3
// 422.519 us; speedup vs baseline: 1.0015x; 1.0015x over previous
//
#include <hip/hip_runtime.h>

#define NB    32
#define LQ    300
#define DM    256
#define NH    8
#define NPTS  12
#define NCOLS 288   // 192 offset cols + 96 attn cols
#define STOT  8400
#define NBQ   (NB * LQ)

#define QB1   16    // queries per projection block
#define T1    320   // 5 waves; threads 288..319 idle after staging

// ---------------------------------------------------------------------------
// Kernel 1: projection. proj[bq][0:192] = q @ W_off + b_off
//                       proj[bq][192:288] = q @ W_attn + b_attn   (fp32)
// Thread j owns output column j for QB1 queries. W reads lane-contiguous
// (coalesced, L2-resident); query rows broadcast from LDS as float4.
// ---------------------------------------------------------------------------
__global__ __launch_bounds__(T1) void msda_proj(
    const float* __restrict__ query,   // (9600, 256)
    const float* __restrict__ Wo,      // (256, 192)
    const float* __restrict__ bo,      // (192)
    const float* __restrict__ Wa,      // (256, 96)
    const float* __restrict__ ba,      // (96)
    float* __restrict__ proj)          // (9600, 288)
{
    __shared__ __align__(16) float q_lds[QB1 * DM];   // 16 KiB
    const int tid = threadIdx.x;
    const int q0  = blockIdx.x * QB1;

    for (int i = tid; i < QB1 * DM; i += T1)
        q_lds[i] = query[(size_t)q0 * DM + i];
    __syncthreads();

    const int j = tid;
    if (j >= NCOLS) return;

    const float* Wp; const float* bp; int stride, jj;
    if (j < 192) { Wp = Wo; bp = bo; stride = 192; jj = j; }
    else         { Wp = Wa; bp = ba; stride = 96;  jj = j - 192; }

    float acc[QB1];
#pragma unroll
    for (int q = 0; q < QB1; ++q) acc[q] = 0.f;

    for (int k = 0; k < DM; k += 4) {
        float w0 = Wp[(k + 0) * stride + jj];
        float w1 = Wp[(k + 1) * stride + jj];
        float w2 = Wp[(k + 2) * stride + jj];
        float w3 = Wp[(k + 3) * stride + jj];
#pragma unroll
        for (int q = 0; q < QB1; ++q) {
            const float4 qv = *(const float4*)&q_lds[q * DM + k];
            acc[q] = fmaf(qv.x, w0,
                     fmaf(qv.y, w1,
                     fmaf(qv.z, w2,
                     fmaf(qv.w, w3, acc[q]))));
        }
    }

    const float bias = bp[jj];
#pragma unroll
    for (int q = 0; q < QB1; ++q)
        proj[(size_t)(q0 + q) * NCOLS + j] = acc[q] + bias;
}

// ---------------------------------------------------------------------------
// Kernel 2: softmax + bilinear sampling + weighted sum. Pure gather kernel:
// no LDS, no barriers. Thread = (bq, head h, lane l); lane owns 4 channels
// h*32 + 4l .. +3. 8 lanes/head-group -> 128B fully-utilized lines per
// corner gather. 48 independent float4 loads per thread, fully unrolled.
//
// v2: XCD-aware block remap. MI355X round-robins physical blocks across the
// 8 XCDs (p % 8). Default bq-ordered blocks replicate every batch's value[]
// (8.6 MB) into all eight 4-MB L2s. Remap so each batch's 75 blocks land on
// one XCD: XCD x serves batches {x, x+8, x+16, x+24}. Bijection:
//   p in [0,2400): x = p&7, k = p>>3 in [0,300),
//   batch = x + 8*(k/75), within = k%75, logical = batch*75 + within.
// Bonus: b == batch, so the bq/300 division disappears.
// ---------------------------------------------------------------------------
__global__ __launch_bounds__(256, 4) void msda_sample(
    const float* __restrict__ value,   // (B, 8400, 256)
    const float* __restrict__ refp,    // (B, LQ, 1, 4)
    const float* __restrict__ proj,    // (9600, 288)
    float4* __restrict__ out)          // (9600, 64) float4 view of (9600,256)
{
    const int p_   = blockIdx.x;
    const int xcd  = p_ & 7;
    const int k_   = p_ >> 3;             // 0..299
    const int grp  = k_ / 75;             // 0..3
    const int within = k_ - 75 * grp;     // 0..74
    const int batch  = xcd + 8 * grp;     // 0..31
    const int lblk   = batch * 75 + within;

    const int gid = lblk * 256 + (int)threadIdx.x;
    const int bq  = gid >> 6;
    const int h   = (gid >> 3) & 7;
    const int l   = gid & 7;
    const int b   = batch;

    const float* pr = proj + (size_t)bq * NCOLS;

    // softmax over the 12 attention logits of head h (redundant per 8 lanes)
    float a[NPTS];
#pragma unroll
    for (int p = 0; p < NPTS; ++p) a[p] = pr[192 + h * NPTS + p];
    float m = a[0];
#pragma unroll
    for (int p = 1; p < NPTS; ++p) m = fmaxf(m, a[p]);
    float s = 0.f;
#pragma unroll
    for (int p = 0; p < NPTS; ++p) { a[p] = __expf(a[p] - m); s += a[p]; }
    const float inv = 1.f / s;

    const float rx = refp[bq * 4 + 0];
    const float ry = refp[bq * 4 + 1];
    const float rw = refp[bq * 4 + 2];
    const float rh = refp[bq * 4 + 3];

    // float4 base for (b, cell 0, head h, channel block l)
    const float4* vb = (const float4*)value + ((size_t)b * STOT * 64 + h * 8 + l);

    float ax = 0.f, ay = 0.f, az = 0.f, aw4 = 0.f;

#pragma unroll
    for (int p = 0; p < NPTS; ++p) {
        const int lvl  = p >> 2;
        const int W    = (lvl == 0) ? 80 : (lvl == 1 ? 40 : 20);
        const int base = (lvl == 0) ? 0  : (lvl == 1 ? 6400 : 8000);

        const float ox = pr[h * 24 + p * 2 + 0];
        const float oy = pr[h * 24 + p * 2 + 1];
        // loc = ref_xy + off * (1/4) * ref_wh * 0.5 ; ix = loc*W - 0.5
        const float ix = fmaf(fmaf(ox, 0.125f * rw, rx), (float)W, -0.5f);
        const float iy = fmaf(fmaf(oy, 0.125f * rh, ry), (float)W, -0.5f);

        const float fx0 = floorf(ix), fy0 = floorf(iy);
        const int x0 = (int)fx0, y0 = (int)fy0;
        const float fx = ix - fx0, fy = iy - fy0;
        const float awt = a[p] * inv;

        const float w00 = awt * (1.f - fx) * (1.f - fy);
        const float w01 = awt * fx * (1.f - fy);
        const float w10 = awt * (1.f - fx) * fy;
        const float w11 = awt * fx * fy;

#pragma unroll
        for (int cnr = 0; cnr < 4; ++cnr) {
            const int x = x0 + (cnr & 1);
            const int y = y0 + (cnr >> 1);
            const float wgt = (cnr == 0) ? w00 : (cnr == 1) ? w01
                             : (cnr == 2) ? w10 : w11;
            const int xc = min(max(x, 0), W - 1);
            const int yc = min(max(y, 0), W - 1);
            const bool ok = (x >= 0) & (x < W) & (y >= 0) & (y < W);
            const float wg = ok ? wgt : 0.f;
            const float4 v = vb[(size_t)(base + yc * W + xc) * 64];
            ax  = fmaf(wg, v.x, ax);
            ay  = fmaf(wg, v.y, ay);
            az  = fmaf(wg, v.z, az);
            aw4 = fmaf(wg, v.w, aw4);
        }
    }

    out[(size_t)bq * 64 + h * 8 + l] = make_float4(ax, ay, az, aw4);
}

extern "C" void kernel_launch(void* const* d_in, const int* in_sizes, int n_in,
                              void* d_out, int out_size, void* d_ws, size_t ws_size,
                              hipStream_t stream) {
    const float* query = (const float*)d_in[0];
    const float* refp  = (const float*)d_in[1];
    const float* vflat = (const float*)d_in[2];
    const float* Woff  = (const float*)d_in[3];
    const float* boff  = (const float*)d_in[4];
    const float* Wattn = (const float*)d_in[5];
    const float* battn = (const float*)d_in[6];
    float4* out = (float4*)d_out;
    float* proj = (float*)d_ws;   // 9600*288*4 = 11.06 MB (ws >= 1.1 GB proven)

    msda_proj<<<dim3(NBQ / QB1), dim3(T1), 0, stream>>>(
        query, Woff, boff, Wattn, battn, proj);
    msda_sample<<<dim3(NBQ * 64 / 256), dim3(256), 0, stream>>>(
        vflat, refp, proj, out);
}